// Round 1
// baseline (439.574 us; speedup 1.0000x reference)
//
#include <hip/hip_runtime.h>

// out[n,:] = ( Σ_{e: dst=n} ci[src_e]·mask_e·ci[n] · feat[e,:] ) @ W^T
//
// R3 restructure: the old scatter issued 19.2M global_atomic_add_f32 ops and
// measured ~53G atomic-ops/s (op-rate bound, NOT sector/BW bound -> ~360us).
// Replace with CSR-build + gather:
//   k_hist   : per-node surviving-edge counts        (~300K int atomics)
//   k_assign : per-wave scan + 1 atomic/wave -> each node a slice [off,off+deg)
//   k_place  : (eid, sv) dropped into slices         (~300K int atomics)
//   k_gather : 1 wave/node, lane=dim, chunk-of-4 edge loop, f32 regs, 1 store
//   rowgemm  : unchanged bf16 MFMA 16x16x32, in-place (R1-verified layout)
// Wide f32 atomics: 19.2M -> 0. Expect memory-bound ~60-90us total.

typedef __attribute__((ext_vector_type(8))) short bf16x8;
typedef __attribute__((ext_vector_type(4))) float f32x4;

static __device__ __forceinline__ short f2bf(float f) {
    union { float f; unsigned u; } v; v.f = f;
    unsigned r = v.u + 0x7FFFu + ((v.u >> 16) & 1u);
    return (short)(r >> 16);
}

// ---- K1: per-node histogram of surviving edges
__global__ __launch_bounds__(256)
void k_hist(const float* __restrict__ mask, const int* __restrict__ dst,
            int* __restrict__ cnt, int E)
{
    int e = blockIdx.x * blockDim.x + threadIdx.x;
    const int stride = gridDim.x * blockDim.x;
    for (; e < E; e += stride) {
        if (mask[e] != 0.0f) atomicAdd(&cnt[dst[e]], 1);
    }
}

// ---- K2: assign each node a private slice via wave-scan + 1 atomic/wave.
// Slices are NOT in global node order (don't need to be): off[n] is each
// node's base, pos[n] a running cursor for placement.
__global__ __launch_bounds__(256)
void k_assign(const int* __restrict__ cnt, int* __restrict__ off,
              int* __restrict__ pos, int* __restrict__ gtotal, int N)
{
    const int lane = threadIdx.x & 63;
    const int n = blockIdx.x * blockDim.x + threadIdx.x;

    int d = (n < N) ? cnt[n] : 0;
    int s = d;                                   // inclusive scan over wave64
#pragma unroll
    for (int o = 1; o < 64; o <<= 1) {
        int u = __shfl_up(s, o, 64);
        if (lane >= o) s += u;
    }
    const int total = __shfl(s, 63, 64);
    int base = 0;
    if (lane == 63) base = atomicAdd(gtotal, total);
    base = __shfl(base, 63, 64);
    const int my = base + s - d;                 // exclusive position
    if (n < N) { off[n] = my; pos[n] = my; }
}

// ---- K3: drop (edge id, sv) of each surviving edge into its node's slice
__global__ __launch_bounds__(256)
void k_place(const float* __restrict__ mask, const float* __restrict__ ci,
             const int* __restrict__ src, const int* __restrict__ dst,
             int* __restrict__ pos, int* __restrict__ eid,
             float* __restrict__ esv, int E)
{
    int e = blockIdx.x * blockDim.x + threadIdx.x;
    const int stride = gridDim.x * blockDim.x;
    for (; e < E; e += stride) {
        const float m = mask[e];
        if (m != 0.0f) {
            const int id = dst[e];
            const float sv = ci[src[e]] * m * ci[id];   // fold dst scale in
            const int p = atomicAdd(&pos[id], 1);
            eid[p] = e;
            esv[p] = sv;
        }
    }
}

// ---- K4: one wave per node; lane = feature dim. Chunk-of-4 edge loop gives
// 8 independent meta loads then 4 independent coalesced 256B row reads.
// Writes every row (deg-0 -> zeros), so no output memset needed.
__global__ __launch_bounds__(256)
void k_gather(const float* __restrict__ feat, const int* __restrict__ cnt,
              const int* __restrict__ off, const int* __restrict__ eid,
              const float* __restrict__ esv, float* __restrict__ g, int N)
{
    const int lane = threadIdx.x & 63;
    int n = (blockIdx.x * blockDim.x + threadIdx.x) >> 6;
    const int nw = (gridDim.x * blockDim.x) >> 6;

    for (; n < N; n += nw) {
        const int d = cnt[n];
        const int o = off[n];
        float h = 0.0f;
        for (int p = 0; p < d; p += 4) {
            const int rem = d - p;
            const int   e0 = eid[o + p];
            const float s0 = esv[o + p];
            int e1 = 0, e2 = 0, e3 = 0;
            float s1 = 0.f, s2 = 0.f, s3 = 0.f;
            if (rem > 1) { e1 = eid[o + p + 1]; s1 = esv[o + p + 1]; }
            if (rem > 2) { e2 = eid[o + p + 2]; s2 = esv[o + p + 2]; }
            if (rem > 3) { e3 = eid[o + p + 3]; s3 = esv[o + p + 3]; }

            h += s0 * feat[(size_t)e0 * 64 + lane];
            if (rem > 1) h += s1 * feat[(size_t)e1 * 64 + lane];
            if (rem > 2) h += s2 * feat[(size_t)e2 * 64 + lane];
            if (rem > 3) h += s3 * feat[(size_t)e3 * 64 + lane];
        }
        g[(size_t)n * 64 + lane] = h;
    }
}

// ---- Pass 2: g[n,:] = g[n,:] @ W^T  (in-place, bf16 MFMA) — unchanged
__global__ __launch_bounds__(256)
void gcn_rowgemm(const float* __restrict__ W,  // [64,64] row-major [f][k]
                 float* __restrict__ g,        // [N,64] in-out
                 int N)
{
    const int lane = threadIdx.x & 63;
    const int wave = threadIdx.x >> 6;
    const int r16  = lane & 15;
    const int q    = lane >> 4;

    // B-frags: B[k][f] = W[f][k]; lane holds f = t*16+r16, k = s*32+q*8+j
    bf16x8 bfrag[4][2];
#pragma unroll
    for (int t = 0; t < 4; ++t) {
        const float* wrow = W + (t * 16 + r16) * 64;
#pragma unroll
        for (int s = 0; s < 2; ++s) {
            const float4 w0 = *(const float4*)(wrow + s * 32 + q * 8);
            const float4 w1 = *(const float4*)(wrow + s * 32 + q * 8 + 4);
            bf16x8 b;
            b[0] = f2bf(w0.x); b[1] = f2bf(w0.y); b[2] = f2bf(w0.z); b[3] = f2bf(w0.w);
            b[4] = f2bf(w1.x); b[5] = f2bf(w1.y); b[6] = f2bf(w1.z); b[7] = f2bf(w1.w);
            bfrag[t][s] = b;
        }
    }

    const int wid = blockIdx.x * 4 + wave;
    const int nw  = gridDim.x * 4;
    for (int n0 = wid * 16; n0 < N; n0 += nw * 16) {
        int ar = n0 + r16;                       // A row (N%16==0; clamp anyway)
        if (ar >= N) ar = N - 1;
        const float* arow = g + (size_t)ar * 64 + q * 8;
        bf16x8 afrag[2];
#pragma unroll
        for (int s = 0; s < 2; ++s) {
            const float4 a0 = *(const float4*)(arow + s * 32);
            const float4 a1 = *(const float4*)(arow + s * 32 + 4);
            bf16x8 a;
            a[0] = f2bf(a0.x); a[1] = f2bf(a0.y); a[2] = f2bf(a0.z); a[3] = f2bf(a0.w);
            a[4] = f2bf(a1.x); a[5] = f2bf(a1.y); a[6] = f2bf(a1.z); a[7] = f2bf(a1.w);
            afrag[s] = a;
        }

        f32x4 acc[4];
#pragma unroll
        for (int t = 0; t < 4; ++t) {
            f32x4 c = {0.f, 0.f, 0.f, 0.f};
            c = __builtin_amdgcn_mfma_f32_16x16x32_bf16(afrag[0], bfrag[t][0], c, 0, 0, 0);
            c = __builtin_amdgcn_mfma_f32_16x16x32_bf16(afrag[1], bfrag[t][1], c, 0, 0, 0);
            acc[t] = c;
        }

        // C layout (R1-verified): row = q*4 + r, col = t*16 + r16.
#pragma unroll
        for (int r = 0; r < 4; ++r) {
            const int orow = n0 + q * 4 + r;
            if (orow < N) {
#pragma unroll
                for (int t = 0; t < 4; ++t)
                    g[(size_t)orow * 64 + t * 16 + r16] = acc[t][r];
            }
        }
    }
}

extern "C" void kernel_launch(void* const* d_in, const int* in_sizes, int n_in,
                              void* d_out, int out_size, void* d_ws, size_t ws_size,
                              hipStream_t stream) {
    const float* feat = (const float*)d_in[0];
    const float* ci   = (const float*)d_in[1];
    const float* W    = (const float*)d_in[2];
    const float* mask = (const float*)d_in[3];
    const int*   src  = (const int*)d_in[4];
    const int*   dst  = (const int*)d_in[5];
    float* out = (float*)d_out;

    const int E = in_sizes[3];   // drop_mask is [E]
    const int N = in_sizes[1];   // ci is [N]

    // Workspace layout: cnt[N] | gtotal[1] | off[N] | pos[N] | eid[E] | esv[E]
    int*   cnt    = (int*)d_ws;
    int*   gtotal = cnt + N;
    int*   off    = gtotal + 1;
    int*   pos    = off + N;
    int*   eid    = pos + N;
    float* esv    = (float*)(eid + E);

    // zero cnt + gtotal only (~400 KB)
    hipMemsetAsync(d_ws, 0, (size_t)(N + 1) * sizeof(int), stream);

    k_hist  <<<dim3(2048), dim3(256), 0, stream>>>(mask, dst, cnt, E);
    k_assign<<<dim3((N + 255) / 256), dim3(256), 0, stream>>>(cnt, off, pos, gtotal, N);
    k_place <<<dim3(2048), dim3(256), 0, stream>>>(mask, ci, src, dst, pos, eid, esv, E);
    k_gather<<<dim3((N + 3) / 4), dim3(256), 0, stream>>>(feat, cnt, off, eid, esv, out, N);
    gcn_rowgemm<<<dim3(1024), dim3(256), 0, stream>>>(W, out, N);
}

// Round 6
// 375.083 us; speedup vs baseline: 1.1719x; 1.1719x over previous
//
#include <hip/hip_runtime.h>

// out[n,:] = ci[n] * ( (Σ_{e: dst=n} ci[src_e]·mask_e · feat[e,:]) @ W^T )
//
// R6: revert to the R0-proven structure (f32 unsafe atomics into d_out).
// Packed-FP-atomic post-mortem (R2/R4/R5): global_atomic_pk_add_f16 is
// silently dropped on BOTH d_ws and d_out (3 lowerings, identical zero
// output), while f32 fadd works on d_out and int atomics work on d_ws.
// Model: all harness buffers are fine-grained; CDNA3+ supports fine-grained
// f32 global fadd but drops packed f16/bf16 fadd there. => f32 atomics are
// the only usable FP-atomic width; the sector-halving lever is unreachable.
//
// Budget model (fits R0=376.6 and R1=439.6 within 1us): timed region carries
// ~310us of harness 1GB poison fills + our ~66us (scatter ~50, rowgemm ~10,
// memset ~5). Scatter is L2 atomic-dword-rate bound (19.2M f32 atomics).
// One tweak vs R0: survivor pipeline deepened 2 -> 4 (all four 256B feat
// loads issue before any atomic) — pure reordering of proven ops.

typedef __attribute__((ext_vector_type(8))) short bf16x8;
typedef __attribute__((ext_vector_type(4))) float f32x4;

static __device__ __forceinline__ short f2bf(float f) {
    union { float f; unsigned u; } v; v.f = f;
    unsigned r = v.u + 0x7FFFu + ((v.u >> 16) & 1u);
    return (short)(r >> 16);
}

// ---- Pass 1: g[dst[e],:] += (ci[src]*mask*ci[dst]) * feat[e,:]
__global__ __launch_bounds__(256)
void gcn_scatter(const float* __restrict__ feat,  // [E,64]
                 const float* __restrict__ ci,    // [N]
                 const float* __restrict__ mask,  // [E]
                 const int*   __restrict__ src,
                 const int*   __restrict__ dst,
                 float* __restrict__ g,           // [N,64] pre-zeroed (= d_out)
                 int E)
{
    const int lane = threadIdx.x & 63;
    const int wid  = (blockIdx.x * blockDim.x + threadIdx.x) >> 6;
    const int nw   = (gridDim.x * blockDim.x) >> 6;

    for (int base = wid * 64; base < E; base += nw * 64) {
        // dense, fully-coalesced meta for 64 edges; gathers gated on mask!=0
        const int e = base + lane;
        float sv = 0.0f;
        int   db = 0;
        if (e < E) {
            const float m = mask[e];             // 0 for 70% of edges
            if (m != 0.0f) {
                const int id = dst[e];
                sv = ci[src[e]] * m * ci[id];    // fold dst-node scale in
                db = id * 64;
            }
        }
        unsigned long long alive = __ballot(sv != 0.0f);

        // survivors in quads: all four feat loads issue before any atomic
        while (alive) {
            const int j0 = __builtin_ctzll(alive); alive &= alive - 1;
            int j1 = -1, j2 = -1, j3 = -1;
            if (alive) { j1 = __builtin_ctzll(alive); alive &= alive - 1; }
            if (alive) { j2 = __builtin_ctzll(alive); alive &= alive - 1; }
            if (alive) { j3 = __builtin_ctzll(alive); alive &= alive - 1; }

            const float s0 = __shfl(sv, j0, 64);
            const int   b0 = __shfl(db, j0, 64);
            const float v0 = feat[(size_t)(base + j0) * 64 + lane];

            float s1 = 0.f, s2 = 0.f, s3 = 0.f;
            int   b1 = 0, b2 = 0, b3 = 0;
            float v1 = 0.f, v2 = 0.f, v3 = 0.f;
            if (j1 >= 0) {
                s1 = __shfl(sv, j1, 64);
                b1 = __shfl(db, j1, 64);
                v1 = feat[(size_t)(base + j1) * 64 + lane];
            }
            if (j2 >= 0) {
                s2 = __shfl(sv, j2, 64);
                b2 = __shfl(db, j2, 64);
                v2 = feat[(size_t)(base + j2) * 64 + lane];
            }
            if (j3 >= 0) {
                s3 = __shfl(sv, j3, 64);
                b3 = __shfl(db, j3, 64);
                v3 = feat[(size_t)(base + j3) * 64 + lane];
            }

            unsafeAtomicAdd(g + b0 + lane, v0 * s0);
            if (j1 >= 0) unsafeAtomicAdd(g + b1 + lane, v1 * s1);
            if (j2 >= 0) unsafeAtomicAdd(g + b2 + lane, v2 * s2);
            if (j3 >= 0) unsafeAtomicAdd(g + b3 + lane, v3 * s3);
        }
    }
}

// ---- Pass 2: g[n,:] = g[n,:] @ W^T  (in-place, bf16 MFMA)
__global__ __launch_bounds__(256)
void gcn_rowgemm(const float* __restrict__ W,  // [64,64] row-major [f][k]
                 float* __restrict__ g,        // [N,64] in-out
                 int N)
{
    const int lane = threadIdx.x & 63;
    const int wave = threadIdx.x >> 6;
    const int r16  = lane & 15;
    const int q    = lane >> 4;

    // B-frags: B[k][f] = W[f][k]; lane holds f = t*16+r16, k = s*32+q*8+j
    bf16x8 bfrag[4][2];
#pragma unroll
    for (int t = 0; t < 4; ++t) {
        const float* wrow = W + (t * 16 + r16) * 64;
#pragma unroll
        for (int s = 0; s < 2; ++s) {
            const float4 w0 = *(const float4*)(wrow + s * 32 + q * 8);
            const float4 w1 = *(const float4*)(wrow + s * 32 + q * 8 + 4);
            bf16x8 b;
            b[0] = f2bf(w0.x); b[1] = f2bf(w0.y); b[2] = f2bf(w0.z); b[3] = f2bf(w0.w);
            b[4] = f2bf(w1.x); b[5] = f2bf(w1.y); b[6] = f2bf(w1.z); b[7] = f2bf(w1.w);
            bfrag[t][s] = b;
        }
    }

    const int wid = blockIdx.x * 4 + wave;
    const int nw  = gridDim.x * 4;
    for (int n0 = wid * 16; n0 < N; n0 += nw * 16) {
        int ar = n0 + r16;                       // A row (N%16==0; clamp anyway)
        if (ar >= N) ar = N - 1;
        const float* arow = g + (size_t)ar * 64 + q * 8;
        bf16x8 afrag[2];
#pragma unroll
        for (int s = 0; s < 2; ++s) {
            const float4 a0 = *(const float4*)(arow + s * 32);
            const float4 a1 = *(const float4*)(arow + s * 32 + 4);
            bf16x8 a;
            a[0] = f2bf(a0.x); a[1] = f2bf(a0.y); a[2] = f2bf(a0.z); a[3] = f2bf(a0.w);
            a[4] = f2bf(a1.x); a[5] = f2bf(a1.y); a[6] = f2bf(a1.z); a[7] = f2bf(a1.w);
            afrag[s] = a;
        }

        f32x4 acc[4];
#pragma unroll
        for (int t = 0; t < 4; ++t) {
            f32x4 c = {0.f, 0.f, 0.f, 0.f};
            c = __builtin_amdgcn_mfma_f32_16x16x32_bf16(afrag[0], bfrag[t][0], c, 0, 0, 0);
            c = __builtin_amdgcn_mfma_f32_16x16x32_bf16(afrag[1], bfrag[t][1], c, 0, 0, 0);
            acc[t] = c;
        }

        // C layout (R1-verified): row = q*4 + r, col = t*16 + r16.
        // All A reads of this tile complete before stores (data dep); tiles
        // are wave-disjoint, so in-place is safe.
#pragma unroll
        for (int r = 0; r < 4; ++r) {
            const int orow = n0 + q * 4 + r;
            if (orow < N) {
#pragma unroll
                for (int t = 0; t < 4; ++t)
                    g[(size_t)orow * 64 + t * 16 + r16] = acc[t][r];
            }
        }
    }
}

extern "C" void kernel_launch(void* const* d_in, const int* in_sizes, int n_in,
                              void* d_out, int out_size, void* d_ws, size_t ws_size,
                              hipStream_t stream) {
    const float* feat = (const float*)d_in[0];
    const float* ci   = (const float*)d_in[1];
    const float* W    = (const float*)d_in[2];
    const float* mask = (const float*)d_in[3];
    const int*   src  = (const int*)d_in[4];
    const int*   dst  = (const int*)d_in[5];
    float* out = (float*)d_out;

    const int E = in_sizes[3];   // drop_mask is [E]
    const int N = in_sizes[1];   // ci is [N]

    hipMemsetAsync(d_out, 0, (size_t)out_size * sizeof(float), stream);

    gcn_scatter<<<dim3(2048), dim3(256), 0, stream>>>(feat, ci, mask, src, dst, out, E);
    gcn_rowgemm<<<dim3(1024), dim3(256), 0, stream>>>(W, out, N);
}